// Round 6
// baseline (14279.739 us; speedup 1.0000x reference)
//
#include <hip/hip_runtime.h>
#include <hip/hip_fp16.h>

// Problem dims
#define BB   128
#define TT   512
#define INS  64
#define HH   512
#define H2   256
#define FS   16        // flag line stride in ints (64B)
#define RING 4         // h ring depth
#define SLAB 16        // batch rows per team
#define BBHH (BB * HH)

// LDS A-tile strides (bytes per staged h row, incl. 16B pad)
#define STR0 1040      // L0: 512 f16 + 8 pad
#define STR1 2064      // L1: 1024 f16 + 8 pad
#define BUFB (16 * STR1)   // 33024 B per buffer (max of layers); x2 buffers

typedef _Float16 f16;
typedef f16 f16x8 __attribute__((ext_vector_type(8)));
typedef float f32x4 __attribute__((ext_vector_type(4)));

__device__ __forceinline__ float sigmoidf_(float x) {
  return 1.0f / (1.0f + __expf(-x));
}
__device__ __forceinline__ float tanhf_(float x) {
  return 1.0f - 2.0f / (__expf(2.0f * x) + 1.0f);
}
__device__ __forceinline__ f16x8 pack8(float4 q0, float4 q1) {
  f16x8 b;
  b[0]=(f16)q0.x; b[1]=(f16)q0.y; b[2]=(f16)q0.z; b[3]=(f16)q0.w;
  b[4]=(f16)q1.x; b[5]=(f16)q1.y; b[6]=(f16)q1.z; b[7]=(f16)q1.w;
  return b;
}

// LLC-coherent h access (bypass non-coherent per-XCD L2): relaxed agent atomics.
__device__ __forceinline__ f16x8 ldg_h(const f16* p) {
  union { unsigned long long q[2]; f16x8 v; } u;
  const unsigned long long* qp = (const unsigned long long*)p;
  u.q[0] = __hip_atomic_load(qp,     __ATOMIC_RELAXED, __HIP_MEMORY_SCOPE_AGENT);
  u.q[1] = __hip_atomic_load(qp + 1, __ATOMIC_RELAXED, __HIP_MEMORY_SCOPE_AGENT);
  return u.v;
}
__device__ __forceinline__ void stg_h(f16* p, unsigned int pk) {
  __hip_atomic_store((unsigned int*)p, pk, __ATOMIC_RELAXED, __HIP_MEMORY_SCOPE_AGENT);
}
__device__ __forceinline__ int ldf(const int* p) {
  return __hip_atomic_load(p, __ATOMIC_RELAXED, __HIP_MEMORY_SCOPE_AGENT);
}

// Team-decomposed persistent 2-layer LSTM. 8 independent teams (one per
// 16-row batch slab); team = 8 WGs x 1024 thr: roles 0-3 = layer0 col-quarters,
// 4-7 = layer1 col-quarters. Weights live in VGPRs (fp16 B-fragments); per step
// only the slab's h (16x512 per ring slot) moves LLC<->CU. Sync = per-WG
// monotonic flags polled by wave 0 only, broadcast in-WG via LDS s_ready.
// Flag semantics: flag = steps completed. L0 step s: need all L0 flags >= s
// (h1_{s-1} ready) and L1 flags >= s-3 (ring anti-dep). L1 step u: need
// L0 >= u+1 (h1_u ready) and L1 >= u (h2_{u-1} ready). Ring depth 4 > skew.
__global__ __launch_bounds__(1024, 1) void lstm_team(
    const float* __restrict__ x,
    const float* __restrict__ Wih0, const float* __restrict__ Whh0,
    const float* __restrict__ bih0, const float* __restrict__ bhh0,
    const float* __restrict__ Wih1, const float* __restrict__ Whh1,
    const float* __restrict__ bih1, const float* __restrict__ bhh1,
    int* __restrict__ flags, f16* __restrict__ h1ring, f16* __restrict__ h2ring)
{
  extern __shared__ char sm[];     // 2 x BUFB staged-A buffers
  __shared__ int s_ready;

  const int tid  = threadIdx.x;
  const int team = blockIdx.x >> 3;
  const int role = blockIdx.x & 7;
  const bool isL1 = (role >= 4);
  const int wid  = tid >> 6;
  const int lane = tid & 63;

  const int ngx  = ((role & 3) << 4) + wid;   // global 8-col block idx (0..63)
  const int col0 = lane & 15;                 // B-frag column
  const int kq2  = (lane >> 4) * 16;          // byte offset within 64B k-step
  const int rloc = lane & 15;                 // A-row within slab
  const int row  = team * SLAB + rloc;        // global batch row
  const int hcol = (ngx << 3) + (lane & 7);
  const int rowb = team * SLAB + ((lane >> 4) << 2);
  const bool low = (lane & 8) == 0;
  const bool evn = (lane & 1) == 0;
  const int swz  = (rloc & 7) << 5;           // LDS XOR swizzle (32B units)

  // stage-thread mapping: thread t stages row sr, 16B chunk sc
  const int sr = tid >> 6;
  const int sc = tid & 63;
  const int swzs = (sr & 7) << 5;

  if (tid == 0) s_ready = -1;

  float bias[2];
  #pragma unroll
  for (int n = 0; n < 2; n++) {
    const int c = n * 16 + col0;
    const int g = ((c >> 3) << 9) + (ngx << 3) + (c & 7);
    bias[n] = isL1 ? (bih1[g] + bhh1[g]) : (bih0[g] + bhh0[g]);
  }

  int* tf     = flags + team * 8 * FS;
  int* myflag = tf + role * FS;

  f32x4 cst = {};

  if (!isL1) {
    // ============== LAYER 0: gate quarter, weights in VGPRs ==============
    f16x8 Bf[2][18];
    #pragma unroll
    for (int n = 0; n < 2; n++) {
      const int c = n * 16 + col0;
      const int g = ((c >> 3) << 9) + (ngx << 3) + (c & 7);
      #pragma unroll
      for (int ks = 0; ks < 18; ks++) {
        const int k = ks * 32 + (kq2 >> 1);
        const float* src = (k < INS) ? (Wih0 + (size_t)g * INS + k)
                                     : (Whh0 + (size_t)g * HH + (k - INS));
        Bf[n][ks] = pack8(*(const float4*)src, *(const float4*)(src + 4));
      }
    }
    __syncthreads();   // s_ready init visible

    for (int s = 0; s < TT; ++s) {
      const f16* h1r = h1ring + ((s + 3) & 3) * BBHH;   // h1_{s-1}
      f16*       h1w = h1ring + (s & 3) * BBHH;         // h1_s

      if (wid == 0) {   // fabric poll: 8 lanes, one team flag line each
        const int tA = s, tB = s - 3;
        int spin = 0; float bk = 1.0f;
        for (;;) {
          int v = (lane < 8) ? ldf(tf + lane * FS) : 0x7fffffff;
          bool ok = (lane < 8) ? (v >= ((lane < 4) ? tA : tB)) : true;
          if (__all(ok)) break;
          if (++spin > (1 << 18)) break;   // safety valve
          #pragma unroll
          for (int i = 0; i < 32; i++) bk = __builtin_fmaf(bk, 1.0000001f, 1e-30f);
          asm volatile("" : "+v"(bk));
        }
        asm volatile("" ::: "memory");
        if (lane == 0)
          __hip_atomic_store(&s_ready, s, __ATOMIC_RELEASE, __HIP_MEMORY_SCOPE_WORKGROUP);
      }
      {
        int spin = 0; float bk = 1.0f;
        while (__hip_atomic_load(&s_ready, __ATOMIC_ACQUIRE, __HIP_MEMORY_SCOPE_WORKGROUP) < s) {
          if (++spin > (1 << 20)) break;
          #pragma unroll
          for (int i = 0; i < 8; i++) bk = __builtin_fmaf(bk, 1.0000001f, 1e-30f);
          asm volatile("" : "+v"(bk));
        }
      }

      // stage h1_{s-1} slab -> LDS (swizzled)
      char* buf = sm + (s & 1) * BUFB;
      *(f16x8*)(buf + sr * STR0 + ((sc * 16) ^ swzs)) =
          ldg_h(h1r + (size_t)(team * SLAB + sr) * HH + sc * 8);
      __syncthreads();

      // x part (k 0..63) direct from global
      const float* xb = x + ((size_t)row * TT + s) * INS;
      const int kf = kq2 >> 1;
      f16x8 ax0 = pack8(*(const float4*)(xb + kf), *(const float4*)(xb + kf + 4));
      f16x8 ax1 = pack8(*(const float4*)(xb + 32 + kf), *(const float4*)(xb + 32 + kf + 4));
      f32x4 acc0 = {}, acc1 = {};
      acc0 = __builtin_amdgcn_mfma_f32_16x16x32_f16(ax0, Bf[0][0], acc0, 0, 0, 0);
      acc1 = __builtin_amdgcn_mfma_f32_16x16x32_f16(ax0, Bf[1][0], acc1, 0, 0, 0);
      acc0 = __builtin_amdgcn_mfma_f32_16x16x32_f16(ax1, Bf[0][1], acc0, 0, 0, 0);
      acc1 = __builtin_amdgcn_mfma_f32_16x16x32_f16(ax1, Bf[1][1], acc1, 0, 0, 0);
      // h part (k 64..575) from LDS
      const char* ab = buf + rloc * STR0;
      #pragma unroll
      for (int ks = 2; ks < 18; ks++) {
        f16x8 a = *(const f16x8*)(ab + (((ks * 64 + kq2) - 128) ^ swz));
        acc0 = __builtin_amdgcn_mfma_f32_16x16x32_f16(a, Bf[0][ks], acc0, 0, 0, 0);
        acc1 = __builtin_amdgcn_mfma_f32_16x16x32_f16(a, Bf[1][ks], acc1, 0, 0, 0);
      }

      // LSTM cell (frag0=[i|f], frag1=[g|o]) + packed h store
      float res[4];
      #pragma unroll
      for (int j = 0; j < 4; j++) {
        float v0 = acc0[j] + bias[0];
        float v1 = acc1[j] + bias[1];
        float p0 = __shfl_xor(v0, 8, 64);
        float p1 = __shfl_xor(v1, 8, 64);
        float ip = low ? v0 : p0;
        float fp = low ? p0 : v0;
        float gp = low ? v1 : p1;
        float op = low ? p1 : v1;
        float cn = sigmoidf_(fp) * cst[j] + sigmoidf_(ip) * tanhf_(gp);
        cst[j] = cn;
        res[j] = sigmoidf_(op) * tanhf_(cn);
      }
      #pragma unroll
      for (int j = 0; j < 4; j++) {
        float other = __shfl_xor(res[j], 1, 64);
        if (low && evn) {
          f16 lo_ = (f16)res[j], hi_ = (f16)other;
          unsigned int pk =
              (unsigned int)__builtin_bit_cast(unsigned short, lo_) |
              ((unsigned int)__builtin_bit_cast(unsigned short, hi_) << 16);
          stg_h(h1w + (size_t)(rowb + j) * HH + hcol, pk);
        }
      }
      asm volatile("s_waitcnt vmcnt(0)" ::: "memory");   // h_s at LLC
      __syncthreads();                                   // all waves drained
      if (tid == 0)
        __hip_atomic_store(myflag, s + 1, __ATOMIC_RELAXED, __HIP_MEMORY_SCOPE_AGENT);
    }
  } else {
    // ============== LAYER 1: gate quarter, weights in VGPRs ==============
    f16x8 Bf[2][32];
    #pragma unroll
    for (int n = 0; n < 2; n++) {
      const int c = n * 16 + col0;
      const int g = ((c >> 3) << 9) + (ngx << 3) + (c & 7);
      #pragma unroll
      for (int ks = 0; ks < 32; ks++) {
        const int k = ks * 32 + (kq2 >> 1);
        const float* src = (k < HH) ? (Wih1 + (size_t)g * HH + k)
                                    : (Whh1 + (size_t)g * HH + (k - HH));
        Bf[n][ks] = pack8(*(const float4*)src, *(const float4*)(src + 4));
      }
    }
    __syncthreads();

    for (int u = 0; u < TT; ++u) {
      const f16* h1r = h1ring + (u & 3) * BBHH;         // h1_u
      const f16* h2r = h2ring + ((u + 3) & 3) * BBHH;   // h2_{u-1}
      f16*       h2w = h2ring + (u & 3) * BBHH;         // h2_u

      if (wid == 0) {
        const int tA = u + 1, tB = u;
        int spin = 0; float bk = 1.0f;
        for (;;) {
          int v = (lane < 8) ? ldf(tf + lane * FS) : 0x7fffffff;
          bool ok = (lane < 8) ? (v >= ((lane < 4) ? tA : tB)) : true;
          if (__all(ok)) break;
          if (++spin > (1 << 18)) break;
          #pragma unroll
          for (int i = 0; i < 32; i++) bk = __builtin_fmaf(bk, 1.0000001f, 1e-30f);
          asm volatile("" : "+v"(bk));
        }
        asm volatile("" ::: "memory");
        if (lane == 0)
          __hip_atomic_store(&s_ready, u, __ATOMIC_RELEASE, __HIP_MEMORY_SCOPE_WORKGROUP);
      }
      {
        int spin = 0; float bk = 1.0f;
        while (__hip_atomic_load(&s_ready, __ATOMIC_ACQUIRE, __HIP_MEMORY_SCOPE_WORKGROUP) < u) {
          if (++spin > (1 << 20)) break;
          #pragma unroll
          for (int i = 0; i < 8; i++) bk = __builtin_fmaf(bk, 1.0000001f, 1e-30f);
          asm volatile("" : "+v"(bk));
        }
      }

      // stage [h1_u | h2_{u-1}] slab -> LDS (swizzled)
      char* buf = sm + (u & 1) * BUFB;
      {
        char* dst = buf + sr * STR1;
        *(f16x8*)(dst + ((sc * 16) ^ swzs)) =
            ldg_h(h1r + (size_t)(team * SLAB + sr) * HH + sc * 8);
        *(f16x8*)(dst + 1024 + ((sc * 16) ^ swzs)) =
            ldg_h(h2r + (size_t)(team * SLAB + sr) * HH + sc * 8);
      }
      __syncthreads();

      const char* ab = buf + rloc * STR1;
      f32x4 acc0 = {}, acc1 = {};
      #pragma unroll
      for (int ks = 0; ks < 32; ks++) {
        f16x8 a = *(const f16x8*)(ab + ((ks * 64 + kq2) ^ swz));
        acc0 = __builtin_amdgcn_mfma_f32_16x16x32_f16(a, Bf[0][ks], acc0, 0, 0, 0);
        acc1 = __builtin_amdgcn_mfma_f32_16x16x32_f16(a, Bf[1][ks], acc1, 0, 0, 0);
      }

      float res[4];
      #pragma unroll
      for (int j = 0; j < 4; j++) {
        float v0 = acc0[j] + bias[0];
        float v1 = acc1[j] + bias[1];
        float p0 = __shfl_xor(v0, 8, 64);
        float p1 = __shfl_xor(v1, 8, 64);
        float ip = low ? v0 : p0;
        float fp = low ? p0 : v0;
        float gp = low ? v1 : p1;
        float op = low ? p1 : v1;
        float cn = sigmoidf_(fp) * cst[j] + sigmoidf_(ip) * tanhf_(gp);
        cst[j] = cn;
        res[j] = sigmoidf_(op) * tanhf_(cn);
      }
      #pragma unroll
      for (int j = 0; j < 4; j++) {
        float other = __shfl_xor(res[j], 1, 64);
        if (low && evn) {
          f16 lo_ = (f16)res[j], hi_ = (f16)other;
          unsigned int pk =
              (unsigned int)__builtin_bit_cast(unsigned short, lo_) |
              ((unsigned int)__builtin_bit_cast(unsigned short, hi_) << 16);
          stg_h(h2w + (size_t)(rowb + j) * HH + hcol, pk);
        }
      }
      asm volatile("s_waitcnt vmcnt(0)" ::: "memory");
      __syncthreads();
      if (tid == 0)
        __hip_atomic_store(myflag, u + 1, __ATOMIC_RELAXED, __HIP_MEMORY_SCOPE_AGENT);
    }
  }
}

__global__ void fc1_kernel(const f16* __restrict__ last, const float* __restrict__ w,
                           const float* __restrict__ b, float* __restrict__ z) {
  const int bb = blockIdx.x;   // batch row
  const int j  = threadIdx.x;  // 0..255 output col
  const f16*   lp = last + bb * HH;
  const float* wp = w + j * HH;
  float s = b[j];
  #pragma unroll 8
  for (int k = 0; k < HH; k++) s += (float)lp[k] * wp[k];
  z[bb * H2 + j] = fmaxf(s, 0.0f);
}

__global__ void fc2_kernel(const float* __restrict__ z, const float* __restrict__ w,
                           const float* __restrict__ b, float* __restrict__ out) {
  const int bb = threadIdx.x;  // 0..127
  float s = b[0];
  #pragma unroll 8
  for (int k = 0; k < H2; k++) s += z[bb * H2 + k] * w[k];
  out[bb] = s;
}

extern "C" void kernel_launch(void* const* d_in, const int* in_sizes, int n_in,
                              void* d_out, int out_size, void* d_ws, size_t ws_size,
                              hipStream_t stream) {
  const float* x     = (const float*)d_in[0];
  const float* Wih0  = (const float*)d_in[1];
  const float* Whh0  = (const float*)d_in[2];
  const float* bih0  = (const float*)d_in[3];
  const float* bhh0  = (const float*)d_in[4];
  const float* Wih1  = (const float*)d_in[5];
  const float* Whh1  = (const float*)d_in[6];
  const float* bih1  = (const float*)d_in[7];
  const float* bhh1  = (const float*)d_in[8];
  const float* fc1w  = (const float*)d_in[9];
  const float* fc1b  = (const float*)d_in[10];
  const float* fc2w  = (const float*)d_in[11];
  const float* fc2b  = (const float*)d_in[12];

  char* ws = (char*)d_ws;
  int*  flags = (int*)ws;                                 // 8 teams x 8 roles
  const size_t FLAGS_B = 8192;
  f16*  h1 = (f16*)(ws + FLAGS_B);                        // RING x B x H
  f16*  h2 = h1 + (size_t)RING * BBHH;                    // RING x B x H
  float* z = (float*)(ws + FLAGS_B + (size_t)2 * RING * BBHH * sizeof(f16));

  // zero flags + rings each replay (h_{-1}=h_{-2}=0, flags=0)
  hipMemsetAsync(ws, 0, FLAGS_B + (size_t)2 * RING * BBHH * sizeof(f16), stream);

  const size_t smem = 2 * BUFB;   // 66048 B
  lstm_team<<<64, 1024, smem, stream>>>(x, Wih0, Whh0, bih0, bhh0,
                                        Wih1, Whh1, bih1, bhh1, flags, h1, h2);

  const f16* last = h2 + ((TT - 1) & 3) * BBHH;   // h2_{511}, slot 3
  fc1_kernel<<<BB, 256, 0, stream>>>(last, fc1w, fc1b, z);
  fc2_kernel<<<1, BB, 0, stream>>>(z, fc2w, fc2b, (float*)d_out);
}

// Round 8
// 8003.568 us; speedup vs baseline: 1.7842x; 1.7842x over previous
//
#include <hip/hip_runtime.h>
#include <hip/hip_fp16.h>

// Problem dims
#define BB   128
#define TT   512
#define INS  64
#define HH   512
#define K0   576    // INS + HH (layer0 fused [x | h1] GEMM depth)
#define K1   1024   // HH + HH  (layer1 fused [h1 | h2] GEMM depth)
#define PAD0 584    // LDS pad (16B-aligned rows)
#define PAD1 1032
#define NWG  128
#define NTHR 512
#define H2   256
#define FS   16     // barrier line stride in ints (64B)

typedef _Float16 f16;
typedef f16 f16x4 __attribute__((ext_vector_type(4)));
typedef f16 f16x8 __attribute__((ext_vector_type(8)));
typedef float f32x4 __attribute__((ext_vector_type(4)));

__device__ __forceinline__ float sigmoidf_(float x) {
  return 1.0f / (1.0f + __expf(-x));
}
__device__ __forceinline__ float tanhf_(float x) {
  return 1.0f - 2.0f / (__expf(2.0f * x) + 1.0f);
}

// LLC-coherent h access (bypass non-coherent per-XCD L2): relaxed agent atomics.
__device__ __forceinline__ f16x8 ldg_h(const f16* p) {
  union { unsigned long long q[2]; f16x8 v; } u;
  const unsigned long long* qp = (const unsigned long long*)p;
  u.q[0] = __hip_atomic_load(qp,     __ATOMIC_RELAXED, __HIP_MEMORY_SCOPE_AGENT);
  u.q[1] = __hip_atomic_load(qp + 1, __ATOMIC_RELAXED, __HIP_MEMORY_SCOPE_AGENT);
  return u.v;
}
__device__ __forceinline__ void stg_h(f16* p, unsigned int pk) {
  __hip_atomic_store((unsigned int*)p, pk, __ATOMIC_RELAXED, __HIP_MEMORY_SCOPE_AGENT);
}
__device__ __forceinline__ int ldf(const int* p) {
  return __hip_atomic_load(p, __ATOMIC_RELAXED, __HIP_MEMORY_SCOPE_AGENT);
}

// 64 dependent FMAs (~110ns) of guaranteed-live busy work: keeps VALU duty
// high during waits (DVFS) and rate-limits poll traffic.
#define FMA_BURST(bk)                                                     \
  {                                                                       \
    _Pragma("unroll")                                                     \
    for (int i_ = 0; i_ < 64; i_++)                                       \
      bk = __builtin_fmaf(bk, 1.0000001f, 1e-30f);                        \
    asm volatile("" : "+v"(bk));                                          \
  }

// Persistent fused 2-layer LSTM (r3 structure + busy-wait tree barrier).
// Grid: 128 WGs x 512 threads (8 waves). WG = (mg 0..1, ng 0..63):
// owns M-rows mg*64..+64 and h-columns ng*8..+8 (32 gate rows), both layers.
// waves 0-3 -> layer0 (16 rows each), waves 4-7 -> layer1.
// Superstep s: L0 computes h1_s (s<T), L1 computes h2_{s-1} (s>=1).
// Barrier: arrival tree (16 lines x 8 WGs -> glob -> genp, monotonic, fires
// exactly once per superstep), release tree (head WGs poll genp, fan out to
// 16 ggen lines; in-WG wave0 polls fabric, waves 1-7 spin on LDS mailbox).
// All spins are FMA-busy (no s_sleep, no idle waits except one syncthreads).
__global__ __launch_bounds__(NTHR, 1) void lstm_fused(
    const float* __restrict__ x,
    const float* __restrict__ Wih0, const float* __restrict__ Whh0,
    const float* __restrict__ bih0, const float* __restrict__ bhh0,
    const float* __restrict__ Wih1, const float* __restrict__ Whh1,
    const float* __restrict__ bih1, const float* __restrict__ bhh1,
    int* __restrict__ bar, f16* __restrict__ h1buf, f16* __restrict__ h2buf)
{
  extern __shared__ f16 smem[];
  f16* W0s = smem;                 // [32][PAD0]
  f16* W1s = smem + 32 * PAD0;     // [32][PAD1]
  __shared__ int smb;              // in-WG release mailbox

  const int tid  = threadIdx.x;
  const int wg   = blockIdx.x;
  const int mg   = wg >> 6;
  const int ng   = wg & 63;
  const int wid  = tid >> 6;
  const int lane = tid & 63;

  if (tid == 0) smb = 0;

  // ---- weights -> LDS (fp16), vectorized float4, once ----
  for (int e4 = tid; e4 < 32 * (K0 / 4); e4 += NTHR) {
    int r = e4 / (K0 / 4), k = (e4 - r * (K0 / 4)) * 4;
    int g = ((r >> 3) << 9) + (ng << 3) + (r & 7);
    float4 v = (k < INS)
        ? *reinterpret_cast<const float4*>(Wih0 + g * INS + k)
        : *reinterpret_cast<const float4*>(Whh0 + g * HH + (k - INS));
    f16x4 h; h[0]=(f16)v.x; h[1]=(f16)v.y; h[2]=(f16)v.z; h[3]=(f16)v.w;
    *reinterpret_cast<f16x4*>(&W0s[r * PAD0 + k]) = h;
  }
  for (int e4 = tid; e4 < 32 * (K1 / 4); e4 += NTHR) {
    int r = e4 >> 8, k = (e4 & 255) * 4;
    int g = ((r >> 3) << 9) + (ng << 3) + (r & 7);
    float4 v = (k < HH)
        ? *reinterpret_cast<const float4*>(Wih1 + g * HH + k)
        : *reinterpret_cast<const float4*>(Whh1 + g * HH + (k - HH));
    f16x4 h; h[0]=(f16)v.x; h[1]=(f16)v.y; h[2]=(f16)v.z; h[3]=(f16)v.w;
    *reinterpret_cast<f16x4*>(&W1s[r * PAD1 + k]) = h;
  }

  const bool isL1 = (wid >= 4);
  const int  wrow = mg * 64 + (wid & 3) * 16;
  const int  col0 = lane & 15;
  const int  rA   = lane & 15;
  const int  kq   = (lane >> 4) * 8;
  const int  hcol = (ng << 3) + (lane & 7);
  const bool low  = (lane & 8) == 0;
  const bool evn  = (lane & 1) == 0;

  float bias[2];
  #pragma unroll
  for (int n = 0; n < 2; n++) {
    int c = n * 16 + col0;
    int g = ((c >> 3) << 9) + (ng << 3) + (c & 7);
    bias[n] = isL1 ? (bih1[g] + bhh1[g]) : (bih0[g] + bhh0[g]);
  }
  __syncthreads();   // weights + smb init

  // barrier region layout (lines of FS=16 ints = 64B):
  //  0..15 grp lines (8 WGs each, line = wg&15); 16 glob; 17 genp;
  //  18..33 ggen lines (release group rg = wg>>3, head = (wg&7)==0)
  int* grp   = bar + (wg & 15) * FS;
  int* glob  = bar + 16 * FS;
  int* genp  = bar + 17 * FS;
  int* ggenp = bar + (18 + (wg >> 3)) * FS;
  const bool head = ((wg & 7) == 0);

  f32x4 cst = {};
  float4 xpre0 = {}, xpre1 = {}, xpre2 = {}, xpre3 = {};   // x prefetch (L0)

  for (int s = 0; s <= TT; ++s) {
    const f16* h1r = h1buf + ((s + 1) & 1) * (BB * HH); // h1_{s-1}
    f16*       h1w = h1buf + ((s    ) & 1) * (BB * HH); // h1_s
    const f16* h2r = h2buf + ((s    ) & 1) * (BB * HH); // h2_{s-2}
    f16*       h2w = h2buf + ((s + 1) & 1) * (BB * HH); // h2_{s-1}

    // =========== release wait for superstep s (skip at s==0) ===========
    if (s > 0) {
      // x prefetch rides under the spin (L0 waves only)
      if (!isL1 && s < TT) {
        const float* xb = x + ((size_t)(wrow + rA) * TT + (size_t)s) * INS;
        xpre0 = *reinterpret_cast<const float4*>(xb + kq);
        xpre1 = *reinterpret_cast<const float4*>(xb + kq + 4);
        xpre2 = *reinterpret_cast<const float4*>(xb + 32 + kq);
        xpre3 = *reinterpret_cast<const float4*>(xb + 32 + kq + 4);
      }
      if (wid == 0) {
        const int* pp = head ? genp : ggenp;
        float bk = 1.0f;
        int spin = 0;
        for (;;) {
          int v = (lane == 0) ? ldf(pp) : 0;
          v = __shfl(v, 0, 64);
          if (v >= s) break;
          if (++spin > (1 << 17)) break;   // safety valve
          FMA_BURST(bk);
        }
        if (head && lane == 0)
          __hip_atomic_store(ggenp, s, __ATOMIC_RELAXED, __HIP_MEMORY_SCOPE_AGENT);
        if (lane == 0)
          __hip_atomic_store(&smb, s, __ATOMIC_RELAXED, __HIP_MEMORY_SCOPE_WORKGROUP);
        asm volatile("" ::: "memory");
      } else {
        float bk = 1.0f;
        int spin = 0;
        while (__hip_atomic_load(&smb, __ATOMIC_RELAXED, __HIP_MEMORY_SCOPE_WORKGROUP) < s) {
          if (++spin > (1 << 18)) break;
          FMA_BURST(bk);
        }
        asm volatile("" ::: "memory");
      }
    }

    const bool active = isL1 ? (s >= 1) : (s < TT);
    if (active) {
      const int row = wrow + rA;
      f32x4 acc0 = {}, acc1 = {};

      if (!isL1) {
        // ---- layer0: gates = [x_s | h1_{s-1}] @ [Wih0 | Whh0]^T ----
        float4 q0, q1, q2, q3;
        if (s > 0) { q0 = xpre0; q1 = xpre1; q2 = xpre2; q3 = xpre3; }
        else {
          const float* xb = x + ((size_t)row * TT + (size_t)s) * INS;
          q0 = *reinterpret_cast<const float4*>(xb + kq);
          q1 = *reinterpret_cast<const float4*>(xb + kq + 4);
          q2 = *reinterpret_cast<const float4*>(xb + 32 + kq);
          q3 = *reinterpret_cast<const float4*>(xb + 32 + kq + 4);
        }
        f16x8 ax0, ax1;
        ax0[0]=(f16)q0.x; ax0[1]=(f16)q0.y; ax0[2]=(f16)q0.z; ax0[3]=(f16)q0.w;
        ax0[4]=(f16)q1.x; ax0[5]=(f16)q1.y; ax0[6]=(f16)q1.z; ax0[7]=(f16)q1.w;
        ax1[0]=(f16)q2.x; ax1[1]=(f16)q2.y; ax1[2]=(f16)q2.z; ax1[3]=(f16)q2.w;
        ax1[4]=(f16)q3.x; ax1[5]=(f16)q3.y; ax1[6]=(f16)q3.z; ax1[7]=(f16)q3.w;
        {
          f16x8 b;
          b = *reinterpret_cast<const f16x8*>(&W0s[col0 * PAD0 + kq]);
          acc0 = __builtin_amdgcn_mfma_f32_16x16x32_f16(ax0, b, acc0, 0, 0, 0);
          b = *reinterpret_cast<const f16x8*>(&W0s[(16 + col0) * PAD0 + kq]);
          acc1 = __builtin_amdgcn_mfma_f32_16x16x32_f16(ax0, b, acc1, 0, 0, 0);
          b = *reinterpret_cast<const f16x8*>(&W0s[col0 * PAD0 + 32 + kq]);
          acc0 = __builtin_amdgcn_mfma_f32_16x16x32_f16(ax1, b, acc0, 0, 0, 0);
          b = *reinterpret_cast<const f16x8*>(&W0s[(16 + col0) * PAD0 + 32 + kq]);
          acc1 = __builtin_amdgcn_mfma_f32_16x16x32_f16(ax1, b, acc1, 0, 0, 0);
        }
        #pragma unroll
        for (int c = 0; c < 2; ++c) {
          f16x8 a[8];
          #pragma unroll
          for (int u = 0; u < 8; ++u) {
            const int kh = (c * 8 + u) * 32 + kq;
            a[u] = ldg_h(h1r + row * HH + kh);
          }
          #pragma unroll
          for (int u = 0; u < 8; ++u) {
            const int kk = INS + (c * 8 + u) * 32 + kq;
            f16x8 b0 = *reinterpret_cast<const f16x8*>(&W0s[col0 * PAD0 + kk]);
            f16x8 b1 = *reinterpret_cast<const f16x8*>(&W0s[(16 + col0) * PAD0 + kk]);
            acc0 = __builtin_amdgcn_mfma_f32_16x16x32_f16(a[u], b0, acc0, 0, 0, 0);
            acc1 = __builtin_amdgcn_mfma_f32_16x16x32_f16(a[u], b1, acc1, 0, 0, 0);
          }
        }
      } else {
        // ---- layer1: gates = [h1_{s-1} | h2_{s-2}] @ [Wih1 | Whh1]^T ----
        #pragma unroll
        for (int c = 0; c < 4; ++c) {
          f16x8 a[8];
          #pragma unroll
          for (int u = 0; u < 8; ++u) {
            const int kk = (c * 8 + u) * 32 + kq;
            a[u] = (c < 2) ? ldg_h(h1r + row * HH + kk)
                           : ldg_h(h2r + row * HH + (kk - HH));
          }
          #pragma unroll
          for (int u = 0; u < 8; ++u) {
            const int kk = (c * 8 + u) * 32 + kq;
            f16x8 b0 = *reinterpret_cast<const f16x8*>(&W1s[col0 * PAD1 + kk]);
            f16x8 b1 = *reinterpret_cast<const f16x8*>(&W1s[(16 + col0) * PAD1 + kk]);
            acc0 = __builtin_amdgcn_mfma_f32_16x16x32_f16(a[u], b0, acc0, 0, 0, 0);
            acc1 = __builtin_amdgcn_mfma_f32_16x16x32_f16(a[u], b1, acc1, 0, 0, 0);
          }
        }
      }

      // ---- LSTM cell (frag0 = [i|f], frag1 = [g|o]) ----
      float res[4];
      #pragma unroll
      for (int j = 0; j < 4; j++) {
        float v0 = acc0[j] + bias[0];
        float v1 = acc1[j] + bias[1];
        float p0 = __shfl_xor(v0, 8, 64);
        float p1 = __shfl_xor(v1, 8, 64);
        float ip = low ? v0 : p0;
        float fp = low ? p0 : v0;
        float gp = low ? v1 : p1;
        float op = low ? p1 : v1;
        float cn = sigmoidf_(fp) * cst[j] + sigmoidf_(ip) * tanhf_(gp);
        cst[j] = cn;
        res[j] = sigmoidf_(op) * tanhf_(cn);
      }
      {
        f16* hw = isL1 ? h2w : h1w;
        const int rowb = wrow + ((lane >> 4) << 2);
        #pragma unroll
        for (int j = 0; j < 4; j++) {
          float other = __shfl_xor(res[j], 1, 64);
          if (low && evn) {
            f16 lo_ = (f16)res[j], hi_ = (f16)other;
            unsigned int pk =
                (unsigned int)__builtin_bit_cast(unsigned short, lo_) |
                ((unsigned int)__builtin_bit_cast(unsigned short, hi_) << 16);
            stg_h(hw + (rowb + j) * HH + hcol, pk);
          }
        }
      }
    }

    // =========== arrival for superstep s ===========
    asm volatile("s_waitcnt vmcnt(0)" ::: "memory");  // h stores at LLC (sc1)
    __syncthreads();
    if (tid == 0) {
      int p = __hip_atomic_fetch_add(grp, 1, __ATOMIC_RELAXED, __HIP_MEMORY_SCOPE_AGENT);
      if ((p & 7) == 7) {   // 8 WGs/line -> fires once per superstep
        int q = __hip_atomic_fetch_add(glob, 1, __ATOMIC_RELAXED, __HIP_MEMORY_SCOPE_AGENT);
        if ((q & 15) == 15) // 16 lines -> fires once per superstep
          __hip_atomic_fetch_add(genp, 1, __ATOMIC_RELAXED, __HIP_MEMORY_SCOPE_AGENT);
      }
    }
  }
}

__global__ void fc1_kernel(const f16* __restrict__ last, const float* __restrict__ w,
                           const float* __restrict__ b, float* __restrict__ z) {
  const int bb = blockIdx.x;
  const int j  = threadIdx.x;
  const f16*   lp = last + bb * HH;
  const float* wp = w + j * HH;
  float s = b[j];
  #pragma unroll 8
  for (int k = 0; k < HH; k++) s += (float)lp[k] * wp[k];
  z[bb * H2 + j] = fmaxf(s, 0.0f);
}

__global__ void fc2_kernel(const float* __restrict__ z, const float* __restrict__ w,
                           const float* __restrict__ b, float* __restrict__ out) {
  const int bb = threadIdx.x;
  float s = b[0];
  #pragma unroll 8
  for (int k = 0; k < H2; k++) s += z[bb * H2 + k] * w[k];
  out[bb] = s;
}

extern "C" void kernel_launch(void* const* d_in, const int* in_sizes, int n_in,
                              void* d_out, int out_size, void* d_ws, size_t ws_size,
                              hipStream_t stream) {
  const float* x     = (const float*)d_in[0];
  const float* Wih0  = (const float*)d_in[1];
  const float* Whh0  = (const float*)d_in[2];
  const float* bih0  = (const float*)d_in[3];
  const float* bhh0  = (const float*)d_in[4];
  const float* Wih1  = (const float*)d_in[5];
  const float* Whh1  = (const float*)d_in[6];
  const float* bih1  = (const float*)d_in[7];
  const float* bhh1  = (const float*)d_in[8];
  const float* fc1w  = (const float*)d_in[9];
  const float* fc1b  = (const float*)d_in[10];
  const float* fc2w  = (const float*)d_in[11];
  const float* fc2b  = (const float*)d_in[12];

  char* ws = (char*)d_ws;
  int*  bar = (int*)ws;                          // 8 KB barrier region
  f16*  h1  = (f16*)(ws + 8192);                 // 2 x B x H
  f16*  h2  = h1 + 2 * BB * HH;                  // 2 x B x H
  float* z  = (float*)(ws + 8192 + (size_t)4 * BB * HH * sizeof(f16));

  hipMemsetAsync(ws, 0, 8192 + (size_t)4 * BB * HH * sizeof(f16), stream);

  const size_t smem = (size_t)(32 * PAD0 + 32 * PAD1) * sizeof(f16);
  lstm_fused<<<NWG, NTHR, smem, stream>>>(x, Wih0, Whh0, bih0, bhh0,
                                          Wih1, Whh1, bih1, bhh1, bar, h1, h2);

  const f16* last = h2 + ((TT - 1) & 1) * (BB * HH);  // h2_{T-1}
  fc1_kernel<<<BB, 256, 0, stream>>>(last, fc1w, fc1b, z);
  fc2_kernel<<<1, BB, 0, stream>>>(z, fc2w, fc2b, (float*)d_out);
}